// Round 1
// baseline (913.277 us; speedup 1.0000x reference)
//
#include <hip/hip_runtime.h>

// Problem constants (from reference)
constexpr int kB  = 8;
constexpr int kT  = 2048;
constexpr int kG  = 1024;
constexpr int kNN = 600;
constexpr int kNE = 424;
constexpr int kD  = 1024;
constexpr int kL  = 2;
constexpr int kBNN = kB * kNN;   // 4800
constexpr int kBNE = kB * kNE;   // 3392

// ---------------------------------------------------------------------------
// Segment boundaries from sorted group ids: start/end per (b, g).
// start/end must be zero-initialized (empty groups -> count 0 -> pooled 0).
__global__ void bounds_kernel(const int* __restrict__ gid,
                              int* __restrict__ start, int* __restrict__ endp) {
    int idx = blockIdx.x * 256 + threadIdx.x;
    if (idx >= kB * kT) return;
    int b = idx / kT, t = idx - b * kT;
    int id = gid[idx];
    if (t == 0 || gid[idx - 1] != id) start[b * kG + id] = t;
    if (t == kT - 1 || gid[idx + 1] != id) endp[b * kG + id] = t + 1;
}

// ---------------------------------------------------------------------------
// Fused embedding gather + ragged mean pool, writes nodes-first layout split.
__global__ void pool_kernel(const int* __restrict__ tokens,
                            const int* __restrict__ start,
                            const int* __restrict__ endp,
                            const float* __restrict__ emb,
                            float* __restrict__ nodes,
                            float* __restrict__ edges) {
    int bg = blockIdx.x;                 // [0, kB*kG)
    int b = bg >> 10, g = bg & (kG - 1); // kG == 1024
    int d = threadIdx.x * 4;             // 256 threads * 4 floats = kD
    int s = start[bg], e = endp[bg];
    float4 acc = make_float4(0.f, 0.f, 0.f, 0.f);
    for (int t = s; t < e; ++t) {
        int tok = tokens[b * kT + t];
        const float4 v = *(const float4*)(emb + (size_t)tok * kD + d);
        acc.x += v.x; acc.y += v.y; acc.z += v.z; acc.w += v.w;
    }
    int c = e - s;
    float sc = 1.0f / (float)(c > 0 ? c : 1);
    acc.x *= sc; acc.y *= sc; acc.z *= sc; acc.w *= sc;
    float* dstp = (g < kNN)
        ? (nodes + (size_t)(b * kNN + g) * kD + d)
        : (edges + (size_t)(b * kNE + (g - kNN)) * kD + d);
    *(float4*)dstp = acc;
}

// ---------------------------------------------------------------------------
// msg_in = nodes[src] + edges        (per-edge row)
__global__ void msg_in_kernel(const float* __restrict__ nodes,
                              const float* __restrict__ edges,
                              const int* __restrict__ src,
                              float* __restrict__ outb) {
    int e = blockIdx.x;
    int d = threadIdx.x * 4;
    int s = src[e];
    const float4 a = *(const float4*)(nodes + (size_t)s * kD + d);
    const float4 b = *(const float4*)(edges + (size_t)e * kD + d);
    float4 r = make_float4(a.x + b.x, a.y + b.y, a.z + b.z, a.w + b.w);
    *(float4*)(outb + (size_t)e * kD + d) = r;
}

// edge_in = nodes[src] + nodes[dst]  (per-edge row)
__global__ void edge_in_kernel(const float* __restrict__ nodes,
                               const int* __restrict__ src,
                               const int* __restrict__ dst,
                               float* __restrict__ outb) {
    int e = blockIdx.x;
    int d = threadIdx.x * 4;
    int s = src[e], t = dst[e];
    const float4 a = *(const float4*)(nodes + (size_t)s * kD + d);
    const float4 b = *(const float4*)(nodes + (size_t)t * kD + d);
    float4 r = make_float4(a.x + b.x, a.y + b.y, a.z + b.z, a.w + b.w);
    *(float4*)(outb + (size_t)e * kD + d) = r;
}

// agg[dst[e]] += msg[e]  (float atomics; ~2-way avg contention)
__global__ void scatter_kernel(const float* __restrict__ msg,
                               const int* __restrict__ dst,
                               float* __restrict__ agg) {
    int e = blockIdx.x;
    int d = threadIdx.x * 4;
    int t = dst[e];
    const float4 v = *(const float4*)(msg + (size_t)e * kD + d);
    float* p = agg + (size_t)t * kD + d;
    atomicAdd(p + 0, v.x);
    atomicAdd(p + 1, v.y);
    atomicAdd(p + 2, v.z);
    atomicAdd(p + 3, v.w);
}

// ---------------------------------------------------------------------------
// C[M,1024] (ACCUM ? += : =) maybe-ReLU(A[M,1024] @ W[1024,1024])
// 64x64 output tile / block, BK=16, 256 threads, 4x4 register blocking.
template <int RELU, int ACCUM>
__global__ __launch_bounds__(256) void gemm64(const float* __restrict__ A,
                                              const float* __restrict__ W,
                                              float* __restrict__ C) {
    __shared__ float As[16 * 64];   // transposed: As[k][row]
    __shared__ float Ws[16 * 64];   // Ws[k][col]
    const int tid = threadIdx.x;
    const int tx = tid & 15, ty = tid >> 4;
    const int bx = blockIdx.x, by = blockIdx.y;
    // staging indices
    const int ar = tid >> 2;          // 0..63 row-in-tile
    const int ac = (tid & 3) * 4;     // k offset (float4)
    const int wr = tid >> 4;          // 0..15 k-row
    const int wc = (tid & 15) * 4;    // col-in-tile (float4)
    const float* Ag = A + (size_t)(by * 64 + ar) * kD + ac;
    const float* Wg = W + (size_t)wr * kD + bx * 64 + wc;
    float acc[4][4] = {};
    for (int k0 = 0; k0 < kD; k0 += 16) {
        const float4 av = *(const float4*)(Ag + k0);
        const float4 wv = *(const float4*)(Wg + (size_t)k0 * kD);
        __syncthreads();   // protect previous iteration's LDS reads
        As[(ac + 0) * 64 + ar] = av.x;
        As[(ac + 1) * 64 + ar] = av.y;
        As[(ac + 2) * 64 + ar] = av.z;
        As[(ac + 3) * 64 + ar] = av.w;
        *(float4*)(Ws + wr * 64 + wc) = wv;
        __syncthreads();
#pragma unroll
        for (int kk = 0; kk < 16; ++kk) {
            const float4 a = *(const float4*)(As + kk * 64 + ty * 4);
            const float4 b = *(const float4*)(Ws + kk * 64 + tx * 4);
            const float avr[4] = {a.x, a.y, a.z, a.w};
            const float bvr[4] = {b.x, b.y, b.z, b.w};
#pragma unroll
            for (int i = 0; i < 4; ++i)
#pragma unroll
                for (int j = 0; j < 4; ++j)
                    acc[i][j] += avr[i] * bvr[j];
        }
    }
#pragma unroll
    for (int i = 0; i < 4; ++i) {
        float4 r = make_float4(acc[i][0], acc[i][1], acc[i][2], acc[i][3]);
        if (RELU) {
            r.x = fmaxf(r.x, 0.f); r.y = fmaxf(r.y, 0.f);
            r.z = fmaxf(r.z, 0.f); r.w = fmaxf(r.w, 0.f);
        }
        float* cp = C + (size_t)(by * 64 + ty * 4 + i) * kD + bx * 64 + tx * 4;
        if (ACCUM) {
            const float4 c = *(const float4*)cp;
            r.x += c.x; r.y += c.y; r.z += c.z; r.w += c.w;
        }
        *(float4*)cp = r;
    }
}

// ---------------------------------------------------------------------------
// Final scatter into padded [B, G, D] output (nodes-first per batch).
__global__ void out_kernel(const float* __restrict__ nodes,
                           const float* __restrict__ edges,
                           float* __restrict__ out) {
    size_t i = (size_t)blockIdx.x * 256 + threadIdx.x;  // one float4 each
    int d = (int)(i & 255) * 4;                          // kD/4 == 256
    int bg = (int)(i >> 8);
    int b = bg >> 10, g = bg & (kG - 1);
    const float* srcp = (g < kNN)
        ? (nodes + (size_t)(b * kNN + g) * kD + d)
        : (edges + (size_t)(b * kNE + (g - kNN)) * kD + d);
    *(float4*)(out + (size_t)bg * kD + d) = *(const float4*)srcp;
}

// ---------------------------------------------------------------------------
extern "C" void kernel_launch(void* const* d_in, const int* in_sizes, int n_in,
                              void* d_out, int out_size, void* d_ws, size_t ws_size,
                              hipStream_t stream) {
    const int*   tokens = (const int*)d_in[0];
    const int*   gids   = (const int*)d_in[1];
    // d_in[2] = seg_ids (layout statically known: nodes-first), unused
    const int*   eidx   = (const int*)d_in[3];
    const float* emb    = (const float*)d_in[4];
    const float* Wm     = (const float*)d_in[5];
    const float* Wu     = (const float*)d_in[6];
    const float* We     = (const float*)d_in[7];
    float* out = (float*)d_out;

    // workspace layout (floats)
    float* nodes = (float*)d_ws;                       // [kBNN, kD]
    float* edges = nodes + (size_t)kBNN * kD;          // [kBNE, kD]
    float* buf   = edges + (size_t)kBNE * kD;          // [kBNE, kD] gather buffer
    int*   start = (int*)(buf + (size_t)kBNE * kD);    // [kB*kG]
    int*   endp  = start + kB * kG;                    // [kB*kG]
    // reuse d_out as scratch (dead before final out_kernel):
    float* agg = out;                                  // [kBNN, kD]
    float* msg = out + (size_t)kBNN * kD;              // [kBNE, kD]

    const int* srcIdx = eidx;            // edge_index[0]
    const int* dstIdx = eidx + kBNE;     // edge_index[1]

    hipMemsetAsync(start, 0, (size_t)2 * kB * kG * sizeof(int), stream);
    bounds_kernel<<<(kB * kT + 255) / 256, 256, 0, stream>>>(gids, start, endp);
    pool_kernel<<<kB * kG, 256, 0, stream>>>(tokens, start, endp, emb, nodes, edges);

    for (int l = 0; l < kL; ++l) {
        const float* wm = Wm + (size_t)l * kD * kD;
        const float* wu = Wu + (size_t)l * kD * kD;
        const float* we = We + (size_t)l * kD * kD;
        // msg = relu((nodes[src] + edges) @ W_msg)
        msg_in_kernel<<<kBNE, 256, 0, stream>>>(nodes, edges, srcIdx, buf);
        gemm64<1, 0><<<dim3(kD / 64, kBNE / 64), 256, 0, stream>>>(buf, wm, msg);
        // agg = segment_sum(msg, dst)
        hipMemsetAsync(agg, 0, (size_t)kBNN * kD * sizeof(float), stream);
        scatter_kernel<<<kBNE, 256, 0, stream>>>(msg, dstIdx, agg);
        // edges += (nodes[src] + nodes[dst]) @ W_edge   (old nodes)
        edge_in_kernel<<<kBNE, 256, 0, stream>>>(nodes, srcIdx, dstIdx, buf);
        gemm64<0, 1><<<dim3(kD / 64, kBNE / 64), 256, 0, stream>>>(buf, we, edges);
        // nodes += agg @ W_upd
        gemm64<0, 1><<<dim3(kD / 64, kBNN / 64), 256, 0, stream>>>(agg, wu, nodes);
    }

    out_kernel<<<(kB * kG * kD / 4) / 256, 256, 0, stream>>>(nodes, edges, out);
}

// Round 2
// 345.330 us; speedup vs baseline: 2.6447x; 2.6447x over previous
//
#include <hip/hip_runtime.h>

// Problem constants
constexpr int kB  = 8;
constexpr int kT  = 2048;
constexpr int kG  = 1024;
constexpr int kNN = 600;
constexpr int kNE = 424;
constexpr int kD  = 1024;
constexpr int kL  = 2;
constexpr int kBNN = kB * kNN;   // 4800
constexpr int kBNE = kB * kNE;   // 3392

typedef __attribute__((ext_vector_type(4))) float f32x4;
typedef __attribute__((ext_vector_type(8))) short bf16x8;
typedef __attribute__((address_space(1))) const void gas_t;
typedef __attribute__((address_space(3))) void las_t;

__device__ __forceinline__ unsigned short f2bf(float x) {
    union { float f; unsigned u; } v; v.f = x;
    unsigned r = v.u + 0x7FFF + ((v.u >> 16) & 1);
    return (unsigned short)(r >> 16);
}

__device__ __forceinline__ void glds16(const void* g, void* l) {
    __builtin_amdgcn_global_load_lds((gas_t*)g, (las_t*)l, 16, 0, 0);
}

// ---------------------------------------------------------------------------
__global__ void bounds_kernel(const int* __restrict__ gid,
                              int* __restrict__ start, int* __restrict__ endp) {
    int idx = blockIdx.x * 256 + threadIdx.x;
    if (idx >= kB * kT) return;
    int b = idx / kT, t = idx - b * kT;
    int id = gid[idx];
    if (t == 0 || gid[idx - 1] != id) start[b * kG + id] = t;
    if (t == kT - 1 || gid[idx + 1] != id) endp[b * kG + id] = t + 1;
}

// Fused embedding gather + ragged mean pool -> fp32 masters (nodes-first split)
__global__ void pool_kernel(const int* __restrict__ tokens,
                            const int* __restrict__ start,
                            const int* __restrict__ endp,
                            const float* __restrict__ emb,
                            float* __restrict__ nodes,
                            float* __restrict__ edges) {
    int bg = blockIdx.x;
    int b = bg >> 10, g = bg & (kG - 1);
    int d = threadIdx.x * 4;
    int s = start[bg], e = endp[bg];
    float4 acc = make_float4(0.f, 0.f, 0.f, 0.f);
    for (int t = s; t < e; ++t) {
        int tok = tokens[b * kT + t];
        const float4 v = *(const float4*)(emb + (size_t)tok * kD + d);
        acc.x += v.x; acc.y += v.y; acc.z += v.z; acc.w += v.w;
    }
    int c = e - s;
    float sc = 1.0f / (float)(c > 0 ? c : 1);
    acc.x *= sc; acc.y *= sc; acc.z *= sc; acc.w *= sc;
    float* dstp = (g < kNN)
        ? (nodes + (size_t)(b * kNN + g) * kD + d)
        : (edges + (size_t)(b * kNE + (g - kNN)) * kD + d);
    *(float4*)dstp = acc;
}

// ---------------------------------------------------------------------------
// W [K][N] fp32 -> Wt [N][K] bf16 (cast + transpose), 6 matrices via blockIdx.z
__global__ __launch_bounds__(256) void wtrans_kernel(const float* __restrict__ Wm,
                                                     const float* __restrict__ Wu,
                                                     const float* __restrict__ We,
                                                     unsigned short* __restrict__ Wt) {
    int z = blockIdx.z;
    const float* W = (z < 2) ? (Wm + (size_t)z * kD * kD)
                   : (z < 4) ? (Wu + (size_t)(z - 2) * kD * kD)
                             : (We + (size_t)(z - 4) * kD * kD);
    unsigned short* out = Wt + (size_t)z * kD * kD;
    __shared__ float t[32][33];
    int n0 = blockIdx.x * 32, k0 = blockIdx.y * 32;
    int r = threadIdx.x >> 3, c4 = (threadIdx.x & 7) * 4;
    const float4 v = *(const float4*)(W + (size_t)(k0 + r) * kD + n0 + c4);
    t[r][c4] = v.x; t[r][c4 + 1] = v.y; t[r][c4 + 2] = v.z; t[r][c4 + 3] = v.w;
    __syncthreads();
    ushort4 o;
    o.x = f2bf(t[c4 + 0][r]); o.y = f2bf(t[c4 + 1][r]);
    o.z = f2bf(t[c4 + 2][r]); o.w = f2bf(t[c4 + 3][r]);
    *(ushort4*)(out + (size_t)(n0 + r) * kD + k0 + c4) = o;
}

// ---------------------------------------------------------------------------
// gathers -> bf16 GEMM A-buffers
__global__ void msg_in_kernel(const float* __restrict__ nodes,
                              const float* __restrict__ edges,
                              const int* __restrict__ src,
                              unsigned short* __restrict__ outb) {
    int e = blockIdx.x;
    int d = threadIdx.x * 4;
    int s = src[e];
    const float4 a = *(const float4*)(nodes + (size_t)s * kD + d);
    const float4 b = *(const float4*)(edges + (size_t)e * kD + d);
    ushort4 o;
    o.x = f2bf(a.x + b.x); o.y = f2bf(a.y + b.y);
    o.z = f2bf(a.z + b.z); o.w = f2bf(a.w + b.w);
    *(ushort4*)(outb + (size_t)e * kD + d) = o;
}

__global__ void edge_in_kernel(const float* __restrict__ nodes,
                               const int* __restrict__ src,
                               const int* __restrict__ dst,
                               unsigned short* __restrict__ outb) {
    int e = blockIdx.x;
    int d = threadIdx.x * 4;
    int s = src[e], t = dst[e];
    const float4 a = *(const float4*)(nodes + (size_t)s * kD + d);
    const float4 b = *(const float4*)(nodes + (size_t)t * kD + d);
    ushort4 o;
    o.x = f2bf(a.x + b.x); o.y = f2bf(a.y + b.y);
    o.z = f2bf(a.z + b.z); o.w = f2bf(a.w + b.w);
    *(ushort4*)(outb + (size_t)e * kD + d) = o;
}

// agg[dst[e]] += msg[e]  (fp32 atomics)
__global__ void scatter_kernel(const float* __restrict__ msg,
                               const int* __restrict__ dst,
                               float* __restrict__ agg) {
    int e = blockIdx.x;
    int d = threadIdx.x * 4;
    int t = dst[e];
    const float4 v = *(const float4*)(msg + (size_t)e * kD + d);
    float* p = agg + (size_t)t * kD + d;
    atomicAdd(p + 0, v.x);
    atomicAdd(p + 1, v.y);
    atomicAdd(p + 2, v.z);
    atomicAdd(p + 3, v.w);
}

// fp32 -> bf16 row cast (for agg)
__global__ void cast_kernel(const float* __restrict__ in, unsigned short* __restrict__ outb) {
    int r = blockIdx.x;
    int d = threadIdx.x * 4;
    const float4 v = *(const float4*)(in + (size_t)r * kD + d);
    ushort4 o; o.x = f2bf(v.x); o.y = f2bf(v.y); o.z = f2bf(v.z); o.w = f2bf(v.w);
    *(ushort4*)(outb + (size_t)r * kD + d) = o;
}

// ---------------------------------------------------------------------------
// bf16 MFMA GEMM: C[M,1024] (ACCUM? += : =) maybe-ReLU(A[M,1024] @ Wt^T)
// Wt is [N][K] bf16. 128x128 tile, BK=32, 4 waves (2x2), 16x16x32 MFMA.
template <int RELU, int ACCUM>
__device__ __forceinline__ void gemm_body(const unsigned short* __restrict__ A,
                                          const unsigned short* __restrict__ Wt,
                                          float* __restrict__ C, int M,
                                          char* smem, int bn, int bm) {
    const int tid = threadIdx.x;
    const int lane = tid & 63;
    const int w = tid >> 6;
    const int wr = w >> 1, wc = w & 1;
    const int row0 = bm * 128, col0 = bn * 128;

    // staging source addresses (chunk c = call*256 + tid; row=c>>2, k8=c&3)
    int arow0 = row0 + (tid >> 2);
    int arow1 = row0 + 64 + (tid >> 2);
    if (arow0 >= M) arow0 = M - 1;     // clamp: outputs for pad rows discarded
    if (arow1 >= M) arow1 = M - 1;
    const unsigned short* agp0 = A + (size_t)arow0 * kD + (tid & 3) * 8;
    const unsigned short* agp1 = A + (size_t)arow1 * kD + (tid & 3) * 8;
    const unsigned short* bgp0 = Wt + (size_t)(col0 + (tid >> 2)) * kD + (tid & 3) * 8;
    const unsigned short* bgp1 = Wt + (size_t)(col0 + 64 + (tid >> 2)) * kD + (tid & 3) * 8;
    char* la0 = smem + w * 1024;
    char* la1 = smem + 4096 + w * 1024;
    char* lb0 = smem + 8192 + w * 1024;
    char* lb1 = smem + 12288 + w * 1024;

    f32x4 acc[4][4] = {};
    const int l15 = lane & 15, kg = lane >> 4;
    for (int k0 = 0; k0 < kD; k0 += 32) {
        __syncthreads();                       // prior LDS reads complete
        glds16(agp0 + k0, la0);
        glds16(agp1 + k0, la1);
        glds16(bgp0 + k0, lb0);
        glds16(bgp1 + k0, lb1);
        __syncthreads();                       // drains vmcnt -> LDS valid
        bf16x8 af[4], bf[4];
#pragma unroll
        for (int i = 0; i < 4; ++i) {
            af[i] = *(const bf16x8*)(smem + ((wr * 64 + i * 16 + l15) * 32 + kg * 8) * 2);
            bf[i] = *(const bf16x8*)(smem + 8192 + ((wc * 64 + i * 16 + l15) * 32 + kg * 8) * 2);
        }
#pragma unroll
        for (int i = 0; i < 4; ++i)
#pragma unroll
            for (int j = 0; j < 4; ++j)
                acc[i][j] = __builtin_amdgcn_mfma_f32_16x16x32_bf16(af[i], bf[j], acc[i][j], 0, 0, 0);
    }
    // epilogue: C/D layout col=lane&15, row=(lane>>4)*4+reg
    const int lr = (lane >> 4) * 4;
#pragma unroll
    for (int i = 0; i < 4; ++i) {
        int rbase = row0 + wr * 64 + i * 16 + lr;
#pragma unroll
        for (int j = 0; j < 4; ++j) {
            int col = col0 + wc * 64 + j * 16 + l15;
#pragma unroll
            for (int r = 0; r < 4; ++r) {
                int row = rbase + r;
                if (row < M) {
                    float v = acc[i][j][r];
                    if (RELU) v = fmaxf(v, 0.f);
                    float* cp = C + (size_t)row * kD + col;
                    if (ACCUM) v += *cp;
                    *cp = v;
                }
            }
        }
    }
}

// z=0: msg = relu(bufM @ WtM^T);  z=1: edges += bufE @ WtE^T
__global__ __launch_bounds__(256) void gemm_dual(const unsigned short* __restrict__ A0,
                                                 const unsigned short* __restrict__ B0,
                                                 float* __restrict__ C0,
                                                 const unsigned short* __restrict__ A1,
                                                 const unsigned short* __restrict__ B1,
                                                 float* __restrict__ C1) {
    __shared__ char smem[16384];
    if (blockIdx.z == 0)
        gemm_body<1, 0>(A0, B0, C0, kBNE, smem, blockIdx.x, blockIdx.y);
    else
        gemm_body<0, 1>(A1, B1, C1, kBNE, smem, blockIdx.x, blockIdx.y);
}

// nodes += aggb @ WtU^T
__global__ __launch_bounds__(256) void gemm_node(const unsigned short* __restrict__ A,
                                                 const unsigned short* __restrict__ B,
                                                 float* __restrict__ C) {
    __shared__ char smem[16384];
    gemm_body<0, 1>(A, B, C, kBNN, smem, blockIdx.x, blockIdx.y);
}

// ---------------------------------------------------------------------------
__global__ void out_kernel(const float* __restrict__ nodes,
                           const float* __restrict__ edges,
                           float* __restrict__ out) {
    size_t i = (size_t)blockIdx.x * 256 + threadIdx.x;
    int d = (int)(i & 255) * 4;
    int bg = (int)(i >> 8);
    int b = bg >> 10, g = bg & (kG - 1);
    const float* srcp = (g < kNN)
        ? (nodes + (size_t)(b * kNN + g) * kD + d)
        : (edges + (size_t)(b * kNE + (g - kNN)) * kD + d);
    *(float4*)(out + (size_t)bg * kD + d) = *(const float4*)srcp;
}

// ---------------------------------------------------------------------------
extern "C" void kernel_launch(void* const* d_in, const int* in_sizes, int n_in,
                              void* d_out, int out_size, void* d_ws, size_t ws_size,
                              hipStream_t stream) {
    const int*   tokens = (const int*)d_in[0];
    const int*   gids   = (const int*)d_in[1];
    const int*   eidx   = (const int*)d_in[3];
    const float* emb    = (const float*)d_in[4];
    const float* Wm     = (const float*)d_in[5];
    const float* Wu     = (const float*)d_in[6];
    const float* We     = (const float*)d_in[7];
    float* out = (float*)d_out;

    // workspace layout (all offsets 1KB-aligned)
    constexpr size_t szNodes = (size_t)kBNN * kD * 4;   // 19,660,800
    constexpr size_t szEdges = (size_t)kBNE * kD * 4;   // 13,893,632
    constexpr size_t szBufM  = (size_t)kBNE * kD * 2;   //  6,946,816
    constexpr size_t szBufE  = (size_t)kBNE * kD * 2;
    constexpr size_t szAggB  = (size_t)kBNN * kD * 2;   //  9,830,400
    constexpr size_t szWt    = (size_t)6 * kD * kD * 2; // 12,582,912
    char* ws = (char*)d_ws;
    float*          nodes = (float*)ws;
    float*          edges = (float*)(ws + szNodes);
    unsigned short* bufM  = (unsigned short*)(ws + szNodes + szEdges);
    unsigned short* bufE  = (unsigned short*)(ws + szNodes + szEdges + szBufM);
    unsigned short* aggb  = (unsigned short*)(ws + szNodes + szEdges + szBufM + szBufE);
    unsigned short* Wt    = (unsigned short*)(ws + szNodes + szEdges + szBufM + szBufE + szAggB);
    int* start = (int*)(ws + szNodes + szEdges + szBufM + szBufE + szAggB + szWt);
    int* endp  = start + kB * kG;
    // d_out doubles as scratch (fully overwritten by out_kernel):
    float* msg = out;                         // [kBNE][kD]  3,473,408 floats
    float* agg = out + (size_t)kBNE * kD;     // [kBNN][kD]  4,915,200 floats

    const int* srcIdx = eidx;
    const int* dstIdx = eidx + kBNE;
    unsigned short* WtM = Wt;                           // [l][N][K]
    unsigned short* WtU = Wt + (size_t)2 * kD * kD;
    unsigned short* WtE = Wt + (size_t)4 * kD * kD;

    hipMemsetAsync(start, 0, (size_t)2 * kB * kG * sizeof(int), stream);
    bounds_kernel<<<(kB * kT + 255) / 256, 256, 0, stream>>>(gids, start, endp);
    pool_kernel<<<kB * kG, 256, 0, stream>>>(tokens, start, endp, emb, nodes, edges);
    wtrans_kernel<<<dim3(kD / 32, kD / 32, 6), 256, 0, stream>>>(Wm, Wu, We, Wt);

    for (int l = 0; l < kL; ++l) {
        unsigned short* wtm = WtM + (size_t)l * kD * kD;
        unsigned short* wtu = WtU + (size_t)l * kD * kD;
        unsigned short* wte = WtE + (size_t)l * kD * kD;
        msg_in_kernel<<<kBNE, 256, 0, stream>>>(nodes, edges, srcIdx, bufM);
        edge_in_kernel<<<kBNE, 256, 0, stream>>>(nodes, srcIdx, dstIdx, bufE);
        // msg = relu(bufM @ WmT) ; edges += bufE @ WeT   (426 blocks in flight)
        gemm_dual<<<dim3(kD / 128, (kBNE + 127) / 128, 2), 256, 0, stream>>>(
            bufM, wtm, msg, bufE, wte, edges);
        hipMemsetAsync(agg, 0, (size_t)kBNN * kD * sizeof(float), stream);
        scatter_kernel<<<kBNE, 256, 0, stream>>>(msg, dstIdx, agg);
        cast_kernel<<<kBNN, 256, 0, stream>>>(agg, aggb);
        // nodes += aggb @ WuT
        gemm_node<<<dim3(kD / 128, (kBNN + 127) / 128, 1), 256, 0, stream>>>(aggb, wtu, nodes);
    }

    out_kernel<<<(size_t)(kB * kG) * (kD / 4) / 256, 256, 0, stream>>>(nodes, edges, out);
}

// Round 3
// 210.366 us; speedup vs baseline: 4.3414x; 1.6416x over previous
//
#include <hip/hip_runtime.h>

// Problem constants
constexpr int kB  = 8;
constexpr int kT  = 2048;
constexpr int kG  = 1024;
constexpr int kNN = 600;
constexpr int kNE = 424;
constexpr int kD  = 1024;
constexpr int kL  = 2;
constexpr int kBNN = kB * kNN;   // 4800
constexpr int kBNE = kB * kNE;   // 3392

typedef __attribute__((ext_vector_type(4))) float f32x4;
typedef __attribute__((ext_vector_type(8))) short bf16x8;
typedef __attribute__((address_space(1))) const void gas_t;
typedef __attribute__((address_space(3))) void las_t;

__device__ __forceinline__ unsigned short f2bf(float x) {
    union { float f; unsigned u; } v; v.f = x;
    unsigned r = v.u + 0x7FFF + ((v.u >> 16) & 1);
    return (unsigned short)(r >> 16);
}

__device__ __forceinline__ void glds16(const void* g, void* l) {
    __builtin_amdgcn_global_load_lds((gas_t*)g, (las_t*)l, 16, 0, 0);
}

// ---------------------------------------------------------------------------
__global__ void bounds_kernel(const int* __restrict__ gid,
                              int* __restrict__ start, int* __restrict__ endp) {
    int idx = blockIdx.x * 256 + threadIdx.x;
    if (idx >= kB * kT) return;
    int b = idx / kT, t = idx - b * kT;
    int id = gid[idx];
    if (t == 0 || gid[idx - 1] != id) start[b * kG + id] = t;
    if (t == kT - 1 || gid[idx + 1] != id) endp[b * kG + id] = t + 1;
}

// Fused embedding gather + ragged mean pool -> fp32 masters (nodes-first split)
__global__ void pool_kernel(const int* __restrict__ tokens,
                            const int* __restrict__ start,
                            const int* __restrict__ endp,
                            const float* __restrict__ emb,
                            float* __restrict__ nodes,
                            float* __restrict__ edges) {
    int bg = blockIdx.x;
    int b = bg >> 10, g = bg & (kG - 1);
    int d = threadIdx.x * 4;
    int s = start[bg], e = endp[bg];
    float4 acc = make_float4(0.f, 0.f, 0.f, 0.f);
    for (int t = s; t < e; ++t) {
        int tok = tokens[b * kT + t];
        const float4 v = *(const float4*)(emb + (size_t)tok * kD + d);
        acc.x += v.x; acc.y += v.y; acc.z += v.z; acc.w += v.w;
    }
    int c = e - s;
    float sc = 1.0f / (float)(c > 0 ? c : 1);
    acc.x *= sc; acc.y *= sc; acc.z *= sc; acc.w *= sc;
    float* dstp = (g < kNN)
        ? (nodes + (size_t)(b * kNN + g) * kD + d)
        : (edges + (size_t)(b * kNE + (g - kNN)) * kD + d);
    *(float4*)dstp = acc;
}

// ---------------------------------------------------------------------------
// W [K][N] fp32 -> Wt [N][K] bf16 (cast + transpose), 6 matrices via blockIdx.z
__global__ __launch_bounds__(256) void wtrans_kernel(const float* __restrict__ Wm,
                                                     const float* __restrict__ Wu,
                                                     const float* __restrict__ We,
                                                     unsigned short* __restrict__ Wt) {
    int z = blockIdx.z;
    const float* W = (z < 2) ? (Wm + (size_t)z * kD * kD)
                   : (z < 4) ? (Wu + (size_t)(z - 2) * kD * kD)
                             : (We + (size_t)(z - 4) * kD * kD);
    unsigned short* out = Wt + (size_t)z * kD * kD;
    __shared__ float t[32][33];
    int n0 = blockIdx.x * 32, k0 = blockIdx.y * 32;
    int r = threadIdx.x >> 3, c4 = (threadIdx.x & 7) * 4;
    const float4 v = *(const float4*)(W + (size_t)(k0 + r) * kD + n0 + c4);
    t[r][c4] = v.x; t[r][c4 + 1] = v.y; t[r][c4 + 2] = v.z; t[r][c4 + 3] = v.w;
    __syncthreads();
    ushort4 o;
    o.x = f2bf(t[c4 + 0][r]); o.y = f2bf(t[c4 + 1][r]);
    o.z = f2bf(t[c4 + 2][r]); o.w = f2bf(t[c4 + 3][r]);
    *(ushort4*)(out + (size_t)(n0 + r) * kD + k0 + c4) = o;
}

// ---------------------------------------------------------------------------
// fused gathers -> bf16 GEMM A-buffers.  y==0: bufM = nodes[src]+edges
//                                        y==1: bufE = nodes[src]+nodes[dst]
__global__ void gather_kernel(const float* __restrict__ nodes,
                              const float* __restrict__ edges,
                              const int* __restrict__ src,
                              const int* __restrict__ dst,
                              unsigned short* __restrict__ bufM,
                              unsigned short* __restrict__ bufE) {
    int e = blockIdx.x;
    int d = threadIdx.x * 4;
    int s = src[e];
    const float4 a = *(const float4*)(nodes + (size_t)s * kD + d);
    float4 b;
    unsigned short* outp;
    if (blockIdx.y == 0) {
        b = *(const float4*)(edges + (size_t)e * kD + d);
        outp = bufM + (size_t)e * kD + d;
    } else {
        int t = dst[e];
        b = *(const float4*)(nodes + (size_t)t * kD + d);
        outp = bufE + (size_t)e * kD + d;
    }
    ushort4 o;
    o.x = f2bf(a.x + b.x); o.y = f2bf(a.y + b.y);
    o.z = f2bf(a.z + b.z); o.w = f2bf(a.w + b.w);
    *(ushort4*)outp = o;
}

// ---------------------------------------------------------------------------
// bf16 MFMA GEMM core. A [M][1024] bf16, Wt [N][K] bf16 (B^T layout).
// 128x128 tile, BK=32, 4 waves (2x2), 16x16x32 MFMA, fp32 accum.
// MODE 0: Cb[row][col] = bf16(relu(acc))                (msg GEMM)
// MODE 1: atomicAdd(Cf[idx(row)][col], acc)             (edge/update GEMM)
//         idx(row) = idxp ? idxp[row] : row
template <int MODE>
__device__ __forceinline__ void gemm_body(const unsigned short* __restrict__ A,
                                          const unsigned short* __restrict__ Wt,
                                          float* __restrict__ Cf,
                                          unsigned short* __restrict__ Cb,
                                          const int* __restrict__ idxp,
                                          int M, int kbeg, int kend,
                                          char* smem, int bn, int bm) {
    const int tid = threadIdx.x;
    const int lane = tid & 63;
    const int w = tid >> 6;
    const int wr = w >> 1, wc = w & 1;
    const int row0 = bm * 128, col0 = bn * 128;

    int arow0 = row0 + (tid >> 2);
    int arow1 = row0 + 64 + (tid >> 2);
    if (arow0 >= M) arow0 = M - 1;     // clamp: pad-row outputs discarded
    if (arow1 >= M) arow1 = M - 1;
    const unsigned short* agp0 = A + (size_t)arow0 * kD + (tid & 3) * 8;
    const unsigned short* agp1 = A + (size_t)arow1 * kD + (tid & 3) * 8;
    const unsigned short* bgp0 = Wt + (size_t)(col0 + (tid >> 2)) * kD + (tid & 3) * 8;
    const unsigned short* bgp1 = Wt + (size_t)(col0 + 64 + (tid >> 2)) * kD + (tid & 3) * 8;
    char* la0 = smem + w * 1024;
    char* la1 = smem + 4096 + w * 1024;
    char* lb0 = smem + 8192 + w * 1024;
    char* lb1 = smem + 12288 + w * 1024;

    f32x4 acc[4][4] = {};
    const int l15 = lane & 15, kg = lane >> 4;
    for (int k0 = kbeg; k0 < kend; k0 += 32) {
        __syncthreads();
        glds16(agp0 + k0, la0);
        glds16(agp1 + k0, la1);
        glds16(bgp0 + k0, lb0);
        glds16(bgp1 + k0, lb1);
        __syncthreads();
        bf16x8 af[4], bf[4];
#pragma unroll
        for (int i = 0; i < 4; ++i) {
            af[i] = *(const bf16x8*)(smem + ((wr * 64 + i * 16 + l15) * 32 + kg * 8) * 2);
            bf[i] = *(const bf16x8*)(smem + 8192 + ((wc * 64 + i * 16 + l15) * 32 + kg * 8) * 2);
        }
#pragma unroll
        for (int i = 0; i < 4; ++i)
#pragma unroll
            for (int j = 0; j < 4; ++j)
                acc[i][j] = __builtin_amdgcn_mfma_f32_16x16x32_bf16(af[i], bf[j], acc[i][j], 0, 0, 0);
    }
    // epilogue: C/D layout col=lane&15, row=(lane>>4)*4+reg
    const int lr = (lane >> 4) * 4;
    if (MODE == 0) {
#pragma unroll
        for (int i = 0; i < 4; ++i) {
            int rbase = row0 + wr * 64 + i * 16 + lr;
#pragma unroll
            for (int r = 0; r < 4; ++r) {
                int row = rbase + r;
                if (row >= M) continue;
                unsigned short* cp = Cb + (size_t)row * kD;
#pragma unroll
                for (int j = 0; j < 4; ++j) {
                    int col = col0 + wc * 64 + j * 16 + l15;
                    cp[col] = f2bf(fmaxf(acc[i][j][r], 0.f));
                }
            }
        }
    } else {
#pragma unroll
        for (int i = 0; i < 4; ++i) {
            int rbase = row0 + wr * 64 + i * 16 + lr;
#pragma unroll
            for (int r = 0; r < 4; ++r) {
                int row = rbase + r;
                if (row >= M) continue;
                int tgt = idxp ? idxp[row] : row;
                float* cp = Cf + (size_t)tgt * kD;
#pragma unroll
                for (int j = 0; j < 4; ++j) {
                    int col = col0 + wc * 64 + j * 16 + l15;
                    atomicAdd(cp + col, acc[i][j][r]);
                }
            }
        }
    }
}

// z=0: msgb = bf16(relu(bufM @ WtM^T));  z=1: edges += bufE @ WtE^T (atomic)
__global__ __launch_bounds__(256) void gemm_dual(const unsigned short* __restrict__ A0,
                                                 const unsigned short* __restrict__ B0,
                                                 unsigned short* __restrict__ C0,
                                                 const unsigned short* __restrict__ A1,
                                                 const unsigned short* __restrict__ B1,
                                                 float* __restrict__ C1) {
    __shared__ char smem[16384];
    if (blockIdx.z == 0)
        gemm_body<0>(A0, B0, nullptr, C0, nullptr, kBNE, 0, kD, smem, blockIdx.x, blockIdx.y);
    else
        gemm_body<1>(A1, B1, C1, nullptr, nullptr, kBNE, 0, kD, smem, blockIdx.x, blockIdx.y);
}

// nodes[dst[row]] += (msgb @ WtU^T)[row]   (K-split over blockIdx.z)
__global__ __launch_bounds__(256) void gemm_upd(const unsigned short* __restrict__ A,
                                                const unsigned short* __restrict__ B,
                                                float* __restrict__ C,
                                                const int* __restrict__ dstIdx) {
    __shared__ char smem[16384];
    int kb = blockIdx.z * (kD / 2);
    gemm_body<1>(A, B, C, nullptr, dstIdx, kBNE, kb, kb + kD / 2, smem, blockIdx.x, blockIdx.y);
}

// ---------------------------------------------------------------------------
__global__ void out_kernel(const float* __restrict__ nodes,
                           const float* __restrict__ edges,
                           float* __restrict__ out) {
    size_t i = (size_t)blockIdx.x * 256 + threadIdx.x;
    int d = (int)(i & 255) * 4;
    int bg = (int)(i >> 8);
    int b = bg >> 10, g = bg & (kG - 1);
    const float* srcp = (g < kNN)
        ? (nodes + (size_t)(b * kNN + g) * kD + d)
        : (edges + (size_t)(b * kNE + (g - kNN)) * kD + d);
    *(float4*)(out + (size_t)bg * kD + d) = *(const float4*)srcp;
}

// ---------------------------------------------------------------------------
extern "C" void kernel_launch(void* const* d_in, const int* in_sizes, int n_in,
                              void* d_out, int out_size, void* d_ws, size_t ws_size,
                              hipStream_t stream) {
    const int*   tokens = (const int*)d_in[0];
    const int*   gids   = (const int*)d_in[1];
    const int*   eidx   = (const int*)d_in[3];
    const float* emb    = (const float*)d_in[4];
    const float* Wm     = (const float*)d_in[5];
    const float* Wu     = (const float*)d_in[6];
    const float* We     = (const float*)d_in[7];
    float* out = (float*)d_out;

    // workspace layout
    constexpr size_t szNodes = (size_t)kBNN * kD * 4;   // fp32 master
    constexpr size_t szEdges = (size_t)kBNE * kD * 4;   // fp32 master
    constexpr size_t szBufM  = (size_t)kBNE * kD * 2;   // bf16
    constexpr size_t szBufE  = (size_t)kBNE * kD * 2;   // bf16
    constexpr size_t szMsgB  = (size_t)kBNE * kD * 2;   // bf16
    constexpr size_t szWt    = (size_t)6 * kD * kD * 2; // bf16
    char* ws = (char*)d_ws;
    float*          nodes = (float*)ws;
    float*          edges = (float*)(ws + szNodes);
    unsigned short* bufM  = (unsigned short*)(ws + szNodes + szEdges);
    unsigned short* bufE  = (unsigned short*)(ws + szNodes + szEdges + szBufM);
    unsigned short* msgb  = (unsigned short*)(ws + szNodes + szEdges + szBufM + szBufE);
    unsigned short* Wt    = (unsigned short*)(ws + szNodes + szEdges + szBufM + szBufE + szMsgB);
    int* start = (int*)(ws + szNodes + szEdges + szBufM + szBufE + szMsgB + szWt);
    int* endp  = start + kB * kG;

    const int* srcIdx = eidx;
    const int* dstIdx = eidx + kBNE;
    unsigned short* WtM = Wt;                           // [l][N][K]
    unsigned short* WtU = Wt + (size_t)2 * kD * kD;
    unsigned short* WtE = Wt + (size_t)4 * kD * kD;

    hipMemsetAsync(start, 0, (size_t)2 * kB * kG * sizeof(int), stream);
    bounds_kernel<<<(kB * kT + 255) / 256, 256, 0, stream>>>(gids, start, endp);
    pool_kernel<<<kB * kG, 256, 0, stream>>>(tokens, start, endp, emb, nodes, edges);
    wtrans_kernel<<<dim3(kD / 32, kD / 32, 6), 256, 0, stream>>>(Wm, Wu, We, Wt);

    constexpr int mtiles = (kBNE + 127) / 128;   // 27
    for (int l = 0; l < kL; ++l) {
        unsigned short* wtm = WtM + (size_t)l * kD * kD;
        unsigned short* wtu = WtU + (size_t)l * kD * kD;
        unsigned short* wte = WtE + (size_t)l * kD * kD;
        gather_kernel<<<dim3(kBNE, 2), 256, 0, stream>>>(nodes, edges, srcIdx, dstIdx, bufM, bufE);
        // msgb = bf16(relu(bufM @ WmT));  edges += bufE @ WeT
        gemm_dual<<<dim3(kD / 128, mtiles, 2), 256, 0, stream>>>(bufM, wtm, msgb, bufE, wte, edges);
        // nodes += segment_sum(msgb @ WuT, dst)   [linearity of segment_sum]
        gemm_upd<<<dim3(kD / 128, mtiles, 2), 256, 0, stream>>>(msgb, wtu, nodes, dstIdx);
    }

    out_kernel<<<(size_t)(kB * kG) * (kD / 4) / 256, 256, 0, stream>>>(nodes, edges, out);
}

// Round 4
// 186.704 us; speedup vs baseline: 4.8916x; 1.1267x over previous
//
#include <hip/hip_runtime.h>

// Problem constants
constexpr int kB  = 8;
constexpr int kT  = 2048;
constexpr int kG  = 1024;
constexpr int kNN = 600;
constexpr int kNE = 424;
constexpr int kD  = 1024;
constexpr int kL  = 2;
constexpr int kBNN = kB * kNN;   // 4800
constexpr int kBNE = kB * kNE;   // 3392

typedef __attribute__((ext_vector_type(4))) float f32x4;
typedef __attribute__((ext_vector_type(8))) short bf16x8;
typedef __attribute__((address_space(1))) const void gas_t;
typedef __attribute__((address_space(3))) void las_t;

__device__ __forceinline__ unsigned short f2bf(float x) {
    union { float f; unsigned u; } v; v.f = x;
    unsigned r = v.u + 0x7FFF + ((v.u >> 16) & 1);
    return (unsigned short)(r >> 16);
}

__device__ __forceinline__ void glds16(const void* g, void* l) {
    __builtin_amdgcn_global_load_lds((gas_t*)g, (las_t*)l, 16, 0, 0);
}

// out-tensor offsets for direct writes
__device__ __forceinline__ size_t edge_out_off(int row) {    // row in [0,kBNE)
    int b = row / kNE, r = row - b * kNE;
    return ((size_t)(b * kG + kNN + r)) * kD;
}
__device__ __forceinline__ size_t node_out_off(int n) {      // n in [0,kBNN)
    int b = n / kNN, g = n - b * kNN;
    return ((size_t)(b * kG + g)) * kD;
}

// ---------------------------------------------------------------------------
__global__ void bounds_kernel(const int* __restrict__ gid,
                              int* __restrict__ start, int* __restrict__ endp) {
    int idx = blockIdx.x * 256 + threadIdx.x;
    if (idx >= kB * kT) return;
    int b = idx / kT, t = idx - b * kT;
    int id = gid[idx];
    if (t == 0 || gid[idx - 1] != id) start[b * kG + id] = t;
    if (t == kT - 1 || gid[idx + 1] != id) endp[b * kG + id] = t + 1;
}

// Fused embedding gather + ragged mean pool -> fp32 masters (nodes-first split)
__global__ void pool_kernel(const int* __restrict__ tokens,
                            const int* __restrict__ start,
                            const int* __restrict__ endp,
                            const float* __restrict__ emb,
                            float* __restrict__ nodes,
                            float* __restrict__ edges) {
    int bg = blockIdx.x;
    int b = bg >> 10, g = bg & (kG - 1);
    int d = threadIdx.x * 4;
    int s = start[bg], e = endp[bg];
    float4 acc = make_float4(0.f, 0.f, 0.f, 0.f);
    for (int t = s; t < e; ++t) {
        int tok = tokens[b * kT + t];
        const float4 v = *(const float4*)(emb + (size_t)tok * kD + d);
        acc.x += v.x; acc.y += v.y; acc.z += v.z; acc.w += v.w;
    }
    int c = e - s;
    float sc = 1.0f / (float)(c > 0 ? c : 1);
    acc.x *= sc; acc.y *= sc; acc.z *= sc; acc.w *= sc;
    float* dstp = (g < kNN)
        ? (nodes + (size_t)(b * kNN + g) * kD + d)
        : (edges + (size_t)(b * kNE + (g - kNN)) * kD + d);
    *(float4*)dstp = acc;
}

// ---------------------------------------------------------------------------
// W [K][N] fp32 -> Wt [N][K] bf16 (cast + transpose), 6 matrices via blockIdx.z
__global__ __launch_bounds__(256) void wtrans_kernel(const float* __restrict__ Wm,
                                                     const float* __restrict__ Wu,
                                                     const float* __restrict__ We,
                                                     unsigned short* __restrict__ Wt) {
    int z = blockIdx.z;
    const float* W = (z < 2) ? (Wm + (size_t)z * kD * kD)
                   : (z < 4) ? (Wu + (size_t)(z - 2) * kD * kD)
                             : (We + (size_t)(z - 4) * kD * kD);
    unsigned short* out = Wt + (size_t)z * kD * kD;
    __shared__ float t[32][33];
    int n0 = blockIdx.x * 32, k0 = blockIdx.y * 32;
    int r = threadIdx.x >> 3, c4 = (threadIdx.x & 7) * 4;
    const float4 v = *(const float4*)(W + (size_t)(k0 + r) * kD + n0 + c4);
    t[r][c4] = v.x; t[r][c4 + 1] = v.y; t[r][c4 + 2] = v.z; t[r][c4 + 3] = v.w;
    __syncthreads();
    ushort4 o;
    o.x = f2bf(t[c4 + 0][r]); o.y = f2bf(t[c4 + 1][r]);
    o.z = f2bf(t[c4 + 2][r]); o.w = f2bf(t[c4 + 3][r]);
    *(ushort4*)(out + (size_t)(n0 + r) * kD + k0 + c4) = o;
}

// ---------------------------------------------------------------------------
// fused gather: bufM[e] = bf16(nodes[src]+edges[e]); bufE[e] = bf16(nodes[src]+nodes[dst])
__global__ void gather_kernel(const float* __restrict__ nodes,
                              const float* __restrict__ edges,
                              const int* __restrict__ src,
                              const int* __restrict__ dst,
                              unsigned short* __restrict__ bufM,
                              unsigned short* __restrict__ bufE) {
    int e = blockIdx.x;
    int d = threadIdx.x * 4;
    int s = src[e], t = dst[e];
    const float4 a = *(const float4*)(nodes + (size_t)s * kD + d);
    const float4 b = *(const float4*)(edges + (size_t)e * kD + d);
    const float4 c = *(const float4*)(nodes + (size_t)t * kD + d);
    ushort4 om, oe;
    om.x = f2bf(a.x + b.x); om.y = f2bf(a.y + b.y);
    om.z = f2bf(a.z + b.z); om.w = f2bf(a.w + b.w);
    oe.x = f2bf(a.x + c.x); oe.y = f2bf(a.y + c.y);
    oe.z = f2bf(a.z + c.z); oe.w = f2bf(a.w + c.w);
    *(ushort4*)(bufM + (size_t)e * kD + d) = om;
    *(ushort4*)(bufE + (size_t)e * kD + d) = oe;
}

// copy post-L0 nodes into d_out node slots (base values for final atomic adds)
__global__ void node_copy_kernel(const float* __restrict__ nodes,
                                 float* __restrict__ out) {
    int n = blockIdx.x;                // [0, kBNN)
    int d = threadIdx.x * 4;
    *(float4*)(out + node_out_off(n) + d) =
        *(const float4*)(nodes + (size_t)n * kD + d);
}

// ---------------------------------------------------------------------------
// bf16 MFMA GEMM core. A [M][1024] bf16, Wt [N][K] bf16 (B^T layout).
// 128x128 tile, BK=32, 4 waves (2x2), 16x16x32 MFMA, fp32 accum.
// 2-phase double-buffered staging: stage(next) issued before ds_read(cur);
// single __syncthreads per K-step drains the PREVIOUS iteration's stage.
// MODE 0: Cb[row][col] = bf16(relu(acc))                     (msg GEMM)
// MODE 1: Cf[row][col] += acc          (edge GEMM L0; unique rows, full K)
// MODE 2: Of[edge_out_off(row)+col] = Ef[row][col] + acc     (edge GEMM L1)
// MODE 3: atomicAdd(Cf[idxp[row]][col], acc)                 (update L0)
// MODE 4: atomicAdd(Of[node_out_off(idxp[row])+col], acc)    (update L1)
template <int MODE>
__device__ __forceinline__ void gemm_body(const unsigned short* __restrict__ A,
                                          const unsigned short* __restrict__ Wt,
                                          float* __restrict__ Cf,
                                          unsigned short* __restrict__ Cb,
                                          const float* __restrict__ Ef,
                                          const int* __restrict__ idxp,
                                          int M, int kbeg, int kend,
                                          char* smem, int bn, int bm) {
    const int tid = threadIdx.x;
    const int lane = tid & 63;
    const int w = tid >> 6;
    const int wr = w >> 1, wc = w & 1;
    const int row0 = bm * 128, col0 = bn * 128;

    int arow0 = row0 + (tid >> 2);
    int arow1 = row0 + 64 + (tid >> 2);
    if (arow0 >= M) arow0 = M - 1;     // clamp: pad-row outputs discarded
    if (arow1 >= M) arow1 = M - 1;
    const unsigned short* agp0 = A + (size_t)arow0 * kD + (tid & 3) * 8;
    const unsigned short* agp1 = A + (size_t)arow1 * kD + (tid & 3) * 8;
    const unsigned short* bgp0 = Wt + (size_t)(col0 + (tid >> 2)) * kD + (tid & 3) * 8;
    const unsigned short* bgp1 = Wt + (size_t)(col0 + 64 + (tid >> 2)) * kD + (tid & 3) * 8;

    const int woff = w * 1024;
    // stage tile k0 into buffer `buf` (0/1)
    auto stage = [&](int bsel, int k0) {
        char* base = smem + bsel * 16384 + woff;
        glds16(agp0 + k0, base);
        glds16(agp1 + k0, base + 4096);
        glds16(bgp0 + k0, base + 8192);
        glds16(bgp1 + k0, base + 12288);
    };

    const int nt = (kend - kbeg) / 32;
    stage(0, kbeg);

    f32x4 acc[4][4] = {};
    const int l15 = lane & 15, kg = lane >> 4;
    for (int t = 0; t < nt; ++t) {
        char* bufc = smem + (t & 1) * 16384;
        __syncthreads();                      // drains prev stage (vmcnt 0) + sync
        if (t + 1 < nt) stage((t + 1) & 1, kbeg + (t + 1) * 32);
        bf16x8 af[4], bf[4];
#pragma unroll
        for (int i = 0; i < 4; ++i) {
            af[i] = *(const bf16x8*)(bufc + ((wr * 64 + i * 16 + l15) * 32 + kg * 8) * 2);
            bf[i] = *(const bf16x8*)(bufc + 8192 + ((wc * 64 + i * 16 + l15) * 32 + kg * 8) * 2);
        }
#pragma unroll
        for (int i = 0; i < 4; ++i)
#pragma unroll
            for (int j = 0; j < 4; ++j)
                acc[i][j] = __builtin_amdgcn_mfma_f32_16x16x32_bf16(af[i], bf[j], acc[i][j], 0, 0, 0);
    }
    // epilogue: C/D layout col=lane&15, row=(lane>>4)*4+reg
    const int lr = (lane >> 4) * 4;
#pragma unroll
    for (int i = 0; i < 4; ++i) {
        int rbase = row0 + wr * 64 + i * 16 + lr;
#pragma unroll
        for (int r = 0; r < 4; ++r) {
            int row = rbase + r;
            if (row >= M) continue;
            if (MODE == 0) {
                unsigned short* cp = Cb + (size_t)row * kD;
#pragma unroll
                for (int j = 0; j < 4; ++j) {
                    int col = col0 + wc * 64 + j * 16 + l15;
                    cp[col] = f2bf(fmaxf(acc[i][j][r], 0.f));
                }
            } else if (MODE == 1) {
                float* cp = Cf + (size_t)row * kD;
#pragma unroll
                for (int j = 0; j < 4; ++j) {
                    int col = col0 + wc * 64 + j * 16 + l15;
                    cp[col] += acc[i][j][r];
                }
            } else if (MODE == 2) {
                const float* ep = Ef + (size_t)row * kD;
                float* op = Cf + edge_out_off(row);
#pragma unroll
                for (int j = 0; j < 4; ++j) {
                    int col = col0 + wc * 64 + j * 16 + l15;
                    op[col] = ep[col] + acc[i][j][r];
                }
            } else if (MODE == 3) {
                float* cp = Cf + (size_t)idxp[row] * kD;
#pragma unroll
                for (int j = 0; j < 4; ++j) {
                    int col = col0 + wc * 64 + j * 16 + l15;
                    atomicAdd(cp + col, acc[i][j][r]);
                }
            } else {
                float* cp = Cf + node_out_off(idxp[row]);
#pragma unroll
                for (int j = 0; j < 4; ++j) {
                    int col = col0 + wc * 64 + j * 16 + l15;
                    atomicAdd(cp + col, acc[i][j][r]);
                }
            }
        }
    }
}

// L0: z=0 msgb = bf16(relu(bufM @ WtM^T));  z=1 edges += bufE @ WtE^T
__global__ __launch_bounds__(256) void gemm_dual_l0(const unsigned short* __restrict__ A0,
                                                    const unsigned short* __restrict__ B0,
                                                    unsigned short* __restrict__ C0,
                                                    const unsigned short* __restrict__ A1,
                                                    const unsigned short* __restrict__ B1,
                                                    float* __restrict__ C1) {
    __shared__ char smem[32768];
    if (blockIdx.z == 0)
        gemm_body<0>(A0, B0, nullptr, C0, nullptr, nullptr, kBNE, 0, kD, smem, blockIdx.x, blockIdx.y);
    else
        gemm_body<1>(A1, B1, C1, nullptr, nullptr, nullptr, kBNE, 0, kD, smem, blockIdx.x, blockIdx.y);
}

// L1: z=0 msgb = bf16(relu(bufM @ WtM^T));  z=1 out_edges = edges + bufE @ WtE^T
__global__ __launch_bounds__(256) void gemm_dual_l1(const unsigned short* __restrict__ A0,
                                                    const unsigned short* __restrict__ B0,
                                                    unsigned short* __restrict__ C0,
                                                    const unsigned short* __restrict__ A1,
                                                    const unsigned short* __restrict__ B1,
                                                    float* __restrict__ outp,
                                                    const float* __restrict__ edges) {
    __shared__ char smem[32768];
    if (blockIdx.z == 0)
        gemm_body<0>(A0, B0, nullptr, C0, nullptr, nullptr, kBNE, 0, kD, smem, blockIdx.x, blockIdx.y);
    else
        gemm_body<2>(A1, B1, outp, nullptr, edges, nullptr, kBNE, 0, kD, smem, blockIdx.x, blockIdx.y);
}

// nodes[dst[row]] += (msgb @ WtU^T)[row]  (K-split over blockIdx.z; atomics)
__global__ __launch_bounds__(256) void gemm_upd_l0(const unsigned short* __restrict__ A,
                                                   const unsigned short* __restrict__ B,
                                                   float* __restrict__ C,
                                                   const int* __restrict__ dstIdx) {
    __shared__ char smem[32768];
    int kb = blockIdx.z * (kD / 2);
    gemm_body<3>(A, B, C, nullptr, nullptr, dstIdx, kBNE, kb, kb + kD / 2, smem, blockIdx.x, blockIdx.y);
}

// out_nodes[dst[row]] += (msgb @ WtU^T)[row]  (final layer -> d_out directly)
__global__ __launch_bounds__(256) void gemm_upd_l1(const unsigned short* __restrict__ A,
                                                   const unsigned short* __restrict__ B,
                                                   float* __restrict__ outp,
                                                   const int* __restrict__ dstIdx) {
    __shared__ char smem[32768];
    int kb = blockIdx.z * (kD / 2);
    gemm_body<4>(A, B, outp, nullptr, nullptr, dstIdx, kBNE, kb, kb + kD / 2, smem, blockIdx.x, blockIdx.y);
}

// ---------------------------------------------------------------------------
extern "C" void kernel_launch(void* const* d_in, const int* in_sizes, int n_in,
                              void* d_out, int out_size, void* d_ws, size_t ws_size,
                              hipStream_t stream) {
    const int*   tokens = (const int*)d_in[0];
    const int*   gids   = (const int*)d_in[1];
    const int*   eidx   = (const int*)d_in[3];
    const float* emb    = (const float*)d_in[4];
    const float* Wm     = (const float*)d_in[5];
    const float* Wu     = (const float*)d_in[6];
    const float* We     = (const float*)d_in[7];
    float* out = (float*)d_out;

    // workspace layout
    constexpr size_t szNodes = (size_t)kBNN * kD * 4;   // fp32 master
    constexpr size_t szEdges = (size_t)kBNE * kD * 4;   // fp32 master
    constexpr size_t szBufM  = (size_t)kBNE * kD * 2;   // bf16
    constexpr size_t szBufE  = (size_t)kBNE * kD * 2;   // bf16
    constexpr size_t szMsgB  = (size_t)kBNE * kD * 2;   // bf16
    constexpr size_t szWt    = (size_t)6 * kD * kD * 2; // bf16
    char* ws = (char*)d_ws;
    float*          nodes = (float*)ws;
    float*          edges = (float*)(ws + szNodes);
    unsigned short* bufM  = (unsigned short*)(ws + szNodes + szEdges);
    unsigned short* bufE  = (unsigned short*)(ws + szNodes + szEdges + szBufM);
    unsigned short* msgb  = (unsigned short*)(ws + szNodes + szEdges + szBufM + szBufE);
    unsigned short* Wt    = (unsigned short*)(ws + szNodes + szEdges + szBufM + szBufE + szMsgB);
    int* start = (int*)(ws + szNodes + szEdges + szBufM + szBufE + szMsgB + szWt);
    int* endp  = start + kB * kG;

    const int* srcIdx = eidx;
    const int* dstIdx = eidx + kBNE;
    unsigned short* WtM = Wt;                           // [l][N][K]
    unsigned short* WtU = Wt + (size_t)2 * kD * kD;
    unsigned short* WtE = Wt + (size_t)4 * kD * kD;

    hipMemsetAsync(start, 0, (size_t)2 * kB * kG * sizeof(int), stream);
    bounds_kernel<<<(kB * kT + 255) / 256, 256, 0, stream>>>(gids, start, endp);
    pool_kernel<<<kB * kG, 256, 0, stream>>>(tokens, start, endp, emb, nodes, edges);
    wtrans_kernel<<<dim3(kD / 32, kD / 32, 6), 256, 0, stream>>>(Wm, Wu, We, Wt);

    constexpr int mtiles = (kBNE + 127) / 128;   // 27
    const dim3 ggrid(kD / 128, mtiles, 2);

    // ---- layer 0 ----
    gather_kernel<<<kBNE, 256, 0, stream>>>(nodes, edges, srcIdx, dstIdx, bufM, bufE);
    gemm_dual_l0<<<ggrid, 256, 0, stream>>>(bufM, WtM, msgb, bufE, WtE, edges);
    gemm_upd_l0<<<ggrid, 256, 0, stream>>>(msgb, WtU, nodes, dstIdx);

    // ---- layer 1 (writes final values straight into d_out) ----
    gather_kernel<<<kBNE, 256, 0, stream>>>(nodes, edges, srcIdx, dstIdx, bufM, bufE);
    node_copy_kernel<<<kBNN, 256, 0, stream>>>(nodes, out);   // base for atomic adds
    gemm_dual_l1<<<ggrid, 256, 0, stream>>>(bufM, WtM + (size_t)kD * kD, msgb,
                                            bufE, WtE + (size_t)kD * kD, out, edges);
    gemm_upd_l1<<<ggrid, 256, 0, stream>>>(msgb, WtU + (size_t)kD * kD, out, dstIdx);
}

// Round 5
// 173.853 us; speedup vs baseline: 5.2531x; 1.0739x over previous
//
#include <hip/hip_runtime.h>

// Problem constants
constexpr int kB  = 8;
constexpr int kT  = 2048;
constexpr int kG  = 1024;
constexpr int kNN = 600;
constexpr int kNE = 424;
constexpr int kD  = 1024;
constexpr int kL  = 2;
constexpr int kBNN = kB * kNN;   // 4800
constexpr int kBNE = kB * kNE;   // 3392
static_assert(kBNE % 64 == 0, "M tiles exact");

typedef __attribute__((ext_vector_type(4))) float f32x4;
typedef __attribute__((ext_vector_type(8))) short bf16x8;
typedef __attribute__((address_space(1))) const void gas_t;
typedef __attribute__((address_space(3))) void las_t;

__device__ __forceinline__ unsigned short f2bf(float x) {
    union { float f; unsigned u; } v; v.f = x;
    unsigned r = v.u + 0x7FFF + ((v.u >> 16) & 1);
    return (unsigned short)(r >> 16);
}

__device__ __forceinline__ void glds16(const void* g, void* l) {
    __builtin_amdgcn_global_load_lds((gas_t*)g, (las_t*)l, 16, 0, 0);
}

// out-tensor offsets for direct writes
__device__ __forceinline__ size_t edge_out_off(int row) {    // row in [0,kBNE)
    int b = row / kNE, r = row - b * kNE;
    return ((size_t)(b * kG + kNN + r)) * kD;
}
__device__ __forceinline__ size_t node_out_off(int n) {      // n in [0,kBNN)
    int b = n / kNN, g = n - b * kNN;
    return ((size_t)(b * kG + g)) * kD;
}

// ---------------------------------------------------------------------------
__global__ void bounds_kernel(const int* __restrict__ gid,
                              int* __restrict__ start, int* __restrict__ endp) {
    int idx = blockIdx.x * 256 + threadIdx.x;
    if (idx >= kB * kT) return;
    int b = idx / kT, t = idx - b * kT;
    int id = gid[idx];
    if (t == 0 || gid[idx - 1] != id) start[b * kG + id] = t;
    if (t == kT - 1 || gid[idx + 1] != id) endp[b * kG + id] = t + 1;
}

// Fused embedding gather + ragged mean pool -> fp32 masters (nodes-first split)
__global__ void pool_kernel(const int* __restrict__ tokens,
                            const int* __restrict__ start,
                            const int* __restrict__ endp,
                            const float* __restrict__ emb,
                            float* __restrict__ nodes,
                            float* __restrict__ edges) {
    int bg = blockIdx.x;
    int b = bg >> 10, g = bg & (kG - 1);
    int d = threadIdx.x * 4;
    int s = start[bg], e = endp[bg];
    float4 acc = make_float4(0.f, 0.f, 0.f, 0.f);
    for (int t = s; t < e; ++t) {
        int tok = tokens[b * kT + t];
        const float4 v = *(const float4*)(emb + (size_t)tok * kD + d);
        acc.x += v.x; acc.y += v.y; acc.z += v.z; acc.w += v.w;
    }
    int c = e - s;
    float sc = 1.0f / (float)(c > 0 ? c : 1);
    acc.x *= sc; acc.y *= sc; acc.z *= sc; acc.w *= sc;
    float* dstp = (g < kNN)
        ? (nodes + (size_t)(b * kNN + g) * kD + d)
        : (edges + (size_t)(b * kNE + (g - kNN)) * kD + d);
    *(float4*)dstp = acc;
}

// ---------------------------------------------------------------------------
// W [K][N] fp32 -> Wt [N][K] bf16 (cast + transpose), 6 matrices via blockIdx.z
__global__ __launch_bounds__(256) void wtrans_kernel(const float* __restrict__ Wm,
                                                     const float* __restrict__ Wu,
                                                     const float* __restrict__ We,
                                                     unsigned short* __restrict__ Wt) {
    int z = blockIdx.z;
    const float* W = (z < 2) ? (Wm + (size_t)z * kD * kD)
                   : (z < 4) ? (Wu + (size_t)(z - 2) * kD * kD)
                             : (We + (size_t)(z - 4) * kD * kD);
    unsigned short* out = Wt + (size_t)z * kD * kD;
    __shared__ float t[32][33];
    int n0 = blockIdx.x * 32, k0 = blockIdx.y * 32;
    int r = threadIdx.x >> 3, c4 = (threadIdx.x & 7) * 4;
    const float4 v = *(const float4*)(W + (size_t)(k0 + r) * kD + n0 + c4);
    t[r][c4] = v.x; t[r][c4 + 1] = v.y; t[r][c4 + 2] = v.z; t[r][c4 + 3] = v.w;
    __syncthreads();
    ushort4 o;
    o.x = f2bf(t[c4 + 0][r]); o.y = f2bf(t[c4 + 1][r]);
    o.z = f2bf(t[c4 + 2][r]); o.w = f2bf(t[c4 + 3][r]);
    *(ushort4*)(out + (size_t)(n0 + r) * kD + k0 + c4) = o;
}

// ---------------------------------------------------------------------------
// gather (+ optional node->out copy folded in, for L1):
//   block < kBNE:  bufM[e] = bf16(nodes[src]+edges[e]); bufE[e] = bf16(nodes[src]+nodes[dst])
//   block >= kBNE (COPY only): out[node_slot(n)] = nodes[n]
template <int COPY>
__global__ void gather_kernel(const float* __restrict__ nodes,
                              const float* __restrict__ edges,
                              const int* __restrict__ src,
                              const int* __restrict__ dst,
                              unsigned short* __restrict__ bufM,
                              unsigned short* __restrict__ bufE,
                              float* __restrict__ out) {
    int d = threadIdx.x * 4;
    int e = blockIdx.x;
    if (COPY && e >= kBNE) {
        int n = e - kBNE;
        *(float4*)(out + node_out_off(n) + d) =
            *(const float4*)(nodes + (size_t)n * kD + d);
        return;
    }
    int s = src[e], t = dst[e];
    const float4 a = *(const float4*)(nodes + (size_t)s * kD + d);
    const float4 b = *(const float4*)(edges + (size_t)e * kD + d);
    const float4 c = *(const float4*)(nodes + (size_t)t * kD + d);
    ushort4 om, oe;
    om.x = f2bf(a.x + b.x); om.y = f2bf(a.y + b.y);
    om.z = f2bf(a.z + b.z); om.w = f2bf(a.w + b.w);
    oe.x = f2bf(a.x + c.x); oe.y = f2bf(a.y + c.y);
    oe.z = f2bf(a.z + c.z); oe.w = f2bf(a.w + c.w);
    *(ushort4*)(bufM + (size_t)e * kD + d) = om;
    *(ushort4*)(bufE + (size_t)e * kD + d) = oe;
}

// ---------------------------------------------------------------------------
// bf16 MFMA GEMM core. A [M][1024] bf16, Wt [N][K] bf16 (B^T layout).
// 64x128 tile, BK=32, 4 waves (2x2 over 32x64 sub-tiles), 16x16x32 MFMA.
// 2-phase double-buffered staging (one barrier per K-step); M % 64 == 0.
// MODE 0: Cb[row][col] = bf16(relu(acc))                     (msg GEMM)
// MODE 1: Cf[row][col] += acc          (edge GEMM L0; unique rows)
// MODE 2: Of[edge_out_off(row)+col] = Ef[row][col] + acc     (edge GEMM L1)
// MODE 3: atomicAdd(Cf[idxp[row]][col], acc)                 (update L0)
// MODE 4: atomicAdd(Of[node_out_off(idxp[row])+col], acc)    (update L1)
template <int MODE>
__device__ __forceinline__ void gemm_body(const unsigned short* __restrict__ A,
                                          const unsigned short* __restrict__ Wt,
                                          float* __restrict__ Cf,
                                          unsigned short* __restrict__ Cb,
                                          const float* __restrict__ Ef,
                                          const int* __restrict__ idxp,
                                          char* smem, int bn, int bm) {
    const int tid = threadIdx.x;
    const int lane = tid & 63;
    const int w = tid >> 6;
    const int wr = w >> 1, wc = w & 1;
    const int row0 = bm * 64, col0 = bn * 128;

    // staging: A tile 64x32 bf16 (4KB, 1 glds/thread), B tile 128x32 (8KB, 2)
    const unsigned short* agp = A + (size_t)(row0 + (tid >> 2)) * kD + (tid & 3) * 8;
    const unsigned short* bgp0 = Wt + (size_t)(col0 + (tid >> 2)) * kD + (tid & 3) * 8;
    const unsigned short* bgp1 = Wt + (size_t)(col0 + 64 + (tid >> 2)) * kD + (tid & 3) * 8;
    const int woff = w * 1024;
    auto stage = [&](int bsel, int k0) {
        char* base = smem + bsel * 12288 + woff;
        glds16(agp + k0, base);                 // A rows w*16..w*16+15
        glds16(bgp0 + k0, base + 4096);         // B rows w*16..
        glds16(bgp1 + k0, base + 8192);         // B rows 64+w*16..
    };

    constexpr int nt = kD / 32;
    stage(0, 0);

    f32x4 acc[2][4] = {};
    const int l15 = lane & 15, kg = lane >> 4;
    for (int t = 0; t < nt; ++t) {
        char* bufc = smem + (t & 1) * 12288;
        __syncthreads();                      // drains prev stage (vmcnt 0) + sync
        if (t + 1 < nt) stage((t + 1) & 1, (t + 1) * 32);
        bf16x8 af[2], bf[4];
#pragma unroll
        for (int i = 0; i < 2; ++i)
            af[i] = *(const bf16x8*)(bufc + ((wr * 32 + i * 16 + l15) * 32 + kg * 8) * 2);
#pragma unroll
        for (int j = 0; j < 4; ++j)
            bf[j] = *(const bf16x8*)(bufc + 4096 + ((wc * 64 + j * 16 + l15) * 32 + kg * 8) * 2);
#pragma unroll
        for (int i = 0; i < 2; ++i)
#pragma unroll
            for (int j = 0; j < 4; ++j)
                acc[i][j] = __builtin_amdgcn_mfma_f32_16x16x32_bf16(af[i], bf[j], acc[i][j], 0, 0, 0);
    }
    // epilogue: C/D layout col=lane&15, row=(lane>>4)*4+reg
    const int lr = (lane >> 4) * 4;
#pragma unroll
    for (int i = 0; i < 2; ++i) {
        int rbase = row0 + wr * 32 + i * 16 + lr;
#pragma unroll
        for (int r = 0; r < 4; ++r) {
            int row = rbase + r;
            if (MODE == 0) {
                unsigned short* cp = Cb + (size_t)row * kD;
#pragma unroll
                for (int j = 0; j < 4; ++j) {
                    int col = col0 + wc * 64 + j * 16 + l15;
                    cp[col] = f2bf(fmaxf(acc[i][j][r], 0.f));
                }
            } else if (MODE == 1) {
                float* cp = Cf + (size_t)row * kD;
#pragma unroll
                for (int j = 0; j < 4; ++j) {
                    int col = col0 + wc * 64 + j * 16 + l15;
                    cp[col] += acc[i][j][r];
                }
            } else if (MODE == 2) {
                const float* ep = Ef + (size_t)row * kD;
                float* op = Cf + edge_out_off(row);
#pragma unroll
                for (int j = 0; j < 4; ++j) {
                    int col = col0 + wc * 64 + j * 16 + l15;
                    op[col] = ep[col] + acc[i][j][r];
                }
            } else if (MODE == 3) {
                float* cp = Cf + (size_t)idxp[row] * kD;
#pragma unroll
                for (int j = 0; j < 4; ++j) {
                    int col = col0 + wc * 64 + j * 16 + l15;
                    atomicAdd(cp + col, acc[i][j][r]);
                }
            } else {
                float* cp = Cf + node_out_off(idxp[row]);
#pragma unroll
                for (int j = 0; j < 4; ++j) {
                    int col = col0 + wc * 64 + j * 16 + l15;
                    atomicAdd(cp + col, acc[i][j][r]);
                }
            }
        }
    }
}

// L0: z=0 msgb = bf16(relu(bufM @ WtM^T));  z=1 edges += bufE @ WtE^T
__global__ __launch_bounds__(256) void gemm_dual_l0(const unsigned short* __restrict__ A0,
                                                    const unsigned short* __restrict__ B0,
                                                    unsigned short* __restrict__ C0,
                                                    const unsigned short* __restrict__ A1,
                                                    const unsigned short* __restrict__ B1,
                                                    float* __restrict__ C1) {
    __shared__ char smem[24576];
    if (blockIdx.z == 0)
        gemm_body<0>(A0, B0, nullptr, C0, nullptr, nullptr, smem, blockIdx.x, blockIdx.y);
    else
        gemm_body<1>(A1, B1, C1, nullptr, nullptr, nullptr, smem, blockIdx.x, blockIdx.y);
}

// L1: z=0 msgb = bf16(relu(bufM @ WtM^T));  z=1 out_edges = edges + bufE @ WtE^T
__global__ __launch_bounds__(256) void gemm_dual_l1(const unsigned short* __restrict__ A0,
                                                    const unsigned short* __restrict__ B0,
                                                    unsigned short* __restrict__ C0,
                                                    const unsigned short* __restrict__ A1,
                                                    const unsigned short* __restrict__ B1,
                                                    float* __restrict__ outp,
                                                    const float* __restrict__ edges) {
    __shared__ char smem[24576];
    if (blockIdx.z == 0)
        gemm_body<0>(A0, B0, nullptr, C0, nullptr, nullptr, smem, blockIdx.x, blockIdx.y);
    else
        gemm_body<2>(A1, B1, outp, nullptr, edges, nullptr, smem, blockIdx.x, blockIdx.y);
}

// nodes[dst[row]] += (msgb @ WtU^T)[row]   (full K, one atomic per element)
__global__ __launch_bounds__(256) void gemm_upd_l0(const unsigned short* __restrict__ A,
                                                   const unsigned short* __restrict__ B,
                                                   float* __restrict__ C,
                                                   const int* __restrict__ dstIdx) {
    __shared__ char smem[24576];
    gemm_body<3>(A, B, C, nullptr, nullptr, dstIdx, smem, blockIdx.x, blockIdx.y);
}

// out_nodes[dst[row]] += (msgb @ WtU^T)[row]  (final layer -> d_out directly)
__global__ __launch_bounds__(256) void gemm_upd_l1(const unsigned short* __restrict__ A,
                                                   const unsigned short* __restrict__ B,
                                                   float* __restrict__ outp,
                                                   const int* __restrict__ dstIdx) {
    __shared__ char smem[24576];
    gemm_body<4>(A, B, outp, nullptr, nullptr, dstIdx, smem, blockIdx.x, blockIdx.y);
}

// ---------------------------------------------------------------------------
extern "C" void kernel_launch(void* const* d_in, const int* in_sizes, int n_in,
                              void* d_out, int out_size, void* d_ws, size_t ws_size,
                              hipStream_t stream) {
    const int*   tokens = (const int*)d_in[0];
    const int*   gids   = (const int*)d_in[1];
    const int*   eidx   = (const int*)d_in[3];
    const float* emb    = (const float*)d_in[4];
    const float* Wm     = (const float*)d_in[5];
    const float* Wu     = (const float*)d_in[6];
    const float* We     = (const float*)d_in[7];
    float* out = (float*)d_out;

    // workspace layout
    constexpr size_t szNodes = (size_t)kBNN * kD * 4;   // fp32 master
    constexpr size_t szEdges = (size_t)kBNE * kD * 4;   // fp32 master
    constexpr size_t szBufM  = (size_t)kBNE * kD * 2;   // bf16
    constexpr size_t szBufE  = (size_t)kBNE * kD * 2;   // bf16
    constexpr size_t szMsgB  = (size_t)kBNE * kD * 2;   // bf16
    constexpr size_t szWt    = (size_t)6 * kD * kD * 2; // bf16
    char* ws = (char*)d_ws;
    float*          nodes = (float*)ws;
    float*          edges = (float*)(ws + szNodes);
    unsigned short* bufM  = (unsigned short*)(ws + szNodes + szEdges);
    unsigned short* bufE  = (unsigned short*)(ws + szNodes + szEdges + szBufM);
    unsigned short* msgb  = (unsigned short*)(ws + szNodes + szEdges + szBufM + szBufE);
    unsigned short* Wt    = (unsigned short*)(ws + szNodes + szEdges + szBufM + szBufE + szMsgB);
    int* start = (int*)(ws + szNodes + szEdges + szBufM + szBufE + szMsgB + szWt);
    int* endp  = start + kB * kG;

    const int* srcIdx = eidx;
    const int* dstIdx = eidx + kBNE;
    unsigned short* WtM = Wt;                           // [l][N][K]
    unsigned short* WtU = Wt + (size_t)2 * kD * kD;
    unsigned short* WtE = Wt + (size_t)4 * kD * kD;

    hipMemsetAsync(start, 0, (size_t)2 * kB * kG * sizeof(int), stream);
    bounds_kernel<<<(kB * kT + 255) / 256, 256, 0, stream>>>(gids, start, endp);
    pool_kernel<<<kB * kG, 256, 0, stream>>>(tokens, start, endp, emb, nodes, edges);
    wtrans_kernel<<<dim3(kD / 32, kD / 32, 6), 256, 0, stream>>>(Wm, Wu, We, Wt);

    constexpr int mt = kBNE / 64;                // 53
    const dim3 gdual(kD / 128, mt, 2);           // 848 blocks
    const dim3 gupd(kD / 128, mt, 1);            // 424 blocks, full K

    // ---- layer 0 ----
    gather_kernel<0><<<kBNE, 256, 0, stream>>>(nodes, edges, srcIdx, dstIdx, bufM, bufE, out);
    gemm_dual_l0<<<gdual, 256, 0, stream>>>(bufM, WtM, msgb, bufE, WtE, edges);
    gemm_upd_l0<<<gupd, 256, 0, stream>>>(msgb, WtU, nodes, dstIdx);

    // ---- layer 1 (writes final values straight into d_out) ----
    gather_kernel<1><<<kBNE + kBNN, 256, 0, stream>>>(nodes, edges, srcIdx, dstIdx, bufM, bufE, out);
    gemm_dual_l1<<<gdual, 256, 0, stream>>>(bufM, WtM + (size_t)kD * kD, msgb,
                                            bufE, WtE + (size_t)kD * kD, out, edges);
    gemm_upd_l1<<<gupd, 256, 0, stream>>>(msgb, WtU + (size_t)kD * kD, out, dstIdx);
}

// Round 6
// 166.453 us; speedup vs baseline: 5.4867x; 1.0445x over previous
//
#include <hip/hip_runtime.h>

// Problem constants
constexpr int kB  = 8;
constexpr int kT  = 2048;
constexpr int kG  = 1024;
constexpr int kNN = 600;
constexpr int kNE = 424;
constexpr int kD  = 1024;
constexpr int kL  = 2;
constexpr int kBNN = kB * kNN;   // 4800
constexpr int kBNE = kB * kNE;   // 3392
static_assert(kBNE % 64 == 0, "M tiles exact");

typedef __attribute__((ext_vector_type(4))) float f32x4;
typedef __attribute__((ext_vector_type(8))) short bf16x8;
typedef __attribute__((address_space(1))) const void gas_t;
typedef __attribute__((address_space(3))) void las_t;

__device__ __forceinline__ unsigned short f2bf(float x) {
    union { float f; unsigned u; } v; v.f = x;
    unsigned r = v.u + 0x7FFF + ((v.u >> 16) & 1);
    return (unsigned short)(r >> 16);
}

__device__ __forceinline__ void glds16(const void* g, void* l) {
    __builtin_amdgcn_global_load_lds((gas_t*)g, (las_t*)l, 16, 0, 0);
}

// out-tensor offsets for direct writes
__device__ __forceinline__ size_t edge_out_off(int row) {    // row in [0,kBNE)
    int b = row / kNE, r = row - b * kNE;
    return ((size_t)(b * kG + kNN + r)) * kD;
}
__device__ __forceinline__ size_t node_out_off(int n) {      // n in [0,kBNN)
    int b = n / kNN, g = n - b * kNN;
    return ((size_t)(b * kG + g)) * kD;
}

// ---------------------------------------------------------------------------
// prep kernel: block < kB*kG -> fused embedding gather + ragged mean pool
//              (bounds via binary search over the sorted group-id row);
//              block >= kB*kG -> W [K][N] fp32 -> Wt [N][K] bf16 transpose.
__global__ __launch_bounds__(256) void prep_kernel(const int* __restrict__ tokens,
                                                   const int* __restrict__ gids,
                                                   const float* __restrict__ emb,
                                                   float* __restrict__ nodes,
                                                   float* __restrict__ edges,
                                                   const float* __restrict__ Wm,
                                                   const float* __restrict__ Wu,
                                                   const float* __restrict__ We,
                                                   unsigned short* __restrict__ Wt) {
    __shared__ float tbuf[32][33];
    int bx = blockIdx.x;
    if (bx < kB * kG) {
        int b = bx >> 10, g = bx & (kG - 1);
        int d = threadIdx.x * 4;
        const int* row = gids + (size_t)b * kT;
        // lower_bound(row, g) and lower_bound(row, g+1): ids non-decreasing
        int lo = 0, hi = kT;
        while (lo < hi) { int m = (lo + hi) >> 1; if (row[m] < g) lo = m + 1; else hi = m; }
        int s = lo; hi = kT;
        while (lo < hi) { int m = (lo + hi) >> 1; if (row[m] <= g) lo = m + 1; else hi = m; }
        int e = lo;
        float4 acc = make_float4(0.f, 0.f, 0.f, 0.f);
        for (int t = s; t < e; ++t) {
            int tok = tokens[(size_t)b * kT + t];
            const float4 v = *(const float4*)(emb + (size_t)tok * kD + d);
            acc.x += v.x; acc.y += v.y; acc.z += v.z; acc.w += v.w;
        }
        int c = e - s;
        float sc = 1.0f / (float)(c > 0 ? c : 1);
        acc.x *= sc; acc.y *= sc; acc.z *= sc; acc.w *= sc;
        float* dstp = (g < kNN)
            ? (nodes + (size_t)(b * kNN + g) * kD + d)
            : (edges + (size_t)(b * kNE + (g - kNN)) * kD + d);
        *(float4*)dstp = acc;
    } else {
        int idx = bx - kB * kG;             // [0, 6*1024)
        int z = idx >> 10;
        int rem = idx & 1023;
        int n0 = (rem & 31) * 32, k0 = (rem >> 5) * 32;
        const float* W = (z < 2) ? (Wm + (size_t)z * kD * kD)
                       : (z < 4) ? (Wu + (size_t)(z - 2) * kD * kD)
                                 : (We + (size_t)(z - 4) * kD * kD);
        unsigned short* outp = Wt + (size_t)z * kD * kD;
        int r = threadIdx.x >> 3, c4 = (threadIdx.x & 7) * 4;
        const float4 v = *(const float4*)(W + (size_t)(k0 + r) * kD + n0 + c4);
        tbuf[r][c4] = v.x; tbuf[r][c4 + 1] = v.y; tbuf[r][c4 + 2] = v.z; tbuf[r][c4 + 3] = v.w;
        __syncthreads();
        ushort4 o;
        o.x = f2bf(tbuf[c4 + 0][r]); o.y = f2bf(tbuf[c4 + 1][r]);
        o.z = f2bf(tbuf[c4 + 2][r]); o.w = f2bf(tbuf[c4 + 3][r]);
        *(ushort4*)(outp + (size_t)(n0 + r) * kD + k0 + c4) = o;
    }
}

// ---------------------------------------------------------------------------
// gather (+ optional node->out copy folded in, for L1):
//   block < kBNE:  bufM[e] = bf16(nodes[src]+edges[e]); bufE[e] = bf16(nodes[src]+nodes[dst])
//   block >= kBNE (COPY only): out[node_slot(n)] = nodes[n]
template <int COPY>
__global__ void gather_kernel(const float* __restrict__ nodes,
                              const float* __restrict__ edges,
                              const int* __restrict__ src,
                              const int* __restrict__ dst,
                              unsigned short* __restrict__ bufM,
                              unsigned short* __restrict__ bufE,
                              float* __restrict__ out) {
    int d = threadIdx.x * 4;
    int e = blockIdx.x;
    if (COPY && e >= kBNE) {
        int n = e - kBNE;
        *(float4*)(out + node_out_off(n) + d) =
            *(const float4*)(nodes + (size_t)n * kD + d);
        return;
    }
    int s = src[e], t = dst[e];
    const float4 a = *(const float4*)(nodes + (size_t)s * kD + d);
    const float4 b = *(const float4*)(edges + (size_t)e * kD + d);
    const float4 c = *(const float4*)(nodes + (size_t)t * kD + d);
    ushort4 om, oe;
    om.x = f2bf(a.x + b.x); om.y = f2bf(a.y + b.y);
    om.z = f2bf(a.z + b.z); om.w = f2bf(a.w + b.w);
    oe.x = f2bf(a.x + c.x); oe.y = f2bf(a.y + c.y);
    oe.z = f2bf(a.z + c.z); oe.w = f2bf(a.w + c.w);
    *(ushort4*)(bufM + (size_t)e * kD + d) = om;
    *(ushort4*)(bufE + (size_t)e * kD + d) = oe;
}

// ---------------------------------------------------------------------------
// bf16 MFMA GEMM core. A [M][1024] bf16, Wt [N][K] bf16 (B^T layout).
// 64x128 tile, BK=32, 4 waves (2x2 over 32x64 sub-tiles), 16x16x32 MFMA.
// Double-buffered with COUNTED vmcnt (loads stay in flight across barriers):
//   prologue stages both buffers (3 glds/thread each);
//   per step: vmcnt(3) -> barrier -> ds_read -> lgkmcnt(0) -> barrier ->
//             stage(t+2) -> MFMA.   vmcnt hits 0 only on the peeled last step.
// MODE 0: Cb[row][col] = bf16(relu(acc))                     (msg GEMM)
// MODE 1: Cf[row][col] += acc          (edge GEMM L0; unique rows)
// MODE 2: Of[edge_out_off(row)+col] = Ef[row][col] + acc     (edge GEMM L1)
// MODE 3: atomicAdd(Cf[idxp[row]][col], acc)                 (update L0)
// MODE 4: atomicAdd(Of[node_out_off(idxp[row])+col], acc)    (update L1)
template <int MODE>
__device__ __forceinline__ void gemm_body(const unsigned short* __restrict__ A,
                                          const unsigned short* __restrict__ Wt,
                                          float* __restrict__ Cf,
                                          unsigned short* __restrict__ Cb,
                                          const float* __restrict__ Ef,
                                          const int* __restrict__ idxp,
                                          char* smem, int bn, int bm) {
    const int tid = threadIdx.x;
    const int lane = tid & 63;
    const int w = tid >> 6;
    const int wr = w >> 1, wc = w & 1;
    const int row0 = bm * 64, col0 = bn * 128;

    // staging: A tile 64x32 bf16 (4KB, 1 glds/thread), B tile 128x32 (8KB, 2)
    const unsigned short* agp = A + (size_t)(row0 + (tid >> 2)) * kD + (tid & 3) * 8;
    const unsigned short* bgp0 = Wt + (size_t)(col0 + (tid >> 2)) * kD + (tid & 3) * 8;
    const unsigned short* bgp1 = Wt + (size_t)(col0 + 64 + (tid >> 2)) * kD + (tid & 3) * 8;
    const int woff = w * 1024;
    auto stage = [&](int bsel, int k0) {
        char* base = smem + bsel * 12288 + woff;
        glds16(agp + k0, base);                 // A rows w*16..w*16+15
        glds16(bgp0 + k0, base + 4096);         // B rows w*16..
        glds16(bgp1 + k0, base + 8192);         // B rows 64+w*16..
    };

    constexpr int nt = kD / 32;                 // 32
    stage(0, 0);
    stage(1, 32);

    f32x4 acc[2][4] = {};
    const int l15 = lane & 15, kg = lane >> 4;
    for (int t = 0; t < nt; ++t) {
        char* bufc = smem + (t & 1) * 12288;
        if (t < nt - 1) asm volatile("s_waitcnt vmcnt(3)" ::: "memory");
        else            asm volatile("s_waitcnt vmcnt(0)" ::: "memory");
        __builtin_amdgcn_s_barrier();           // buf[t&1] fully staged for all
        bf16x8 af[2], bf[4];
#pragma unroll
        for (int i = 0; i < 2; ++i)
            af[i] = *(const bf16x8*)(bufc + ((wr * 32 + i * 16 + l15) * 32 + kg * 8) * 2);
#pragma unroll
        for (int j = 0; j < 4; ++j)
            bf[j] = *(const bf16x8*)(bufc + 4096 + ((wc * 64 + j * 16 + l15) * 32 + kg * 8) * 2);
        asm volatile("s_waitcnt lgkmcnt(0)" ::: "memory");  // my reads landed
        __builtin_amdgcn_s_barrier();           // everyone done reading buf[t&1]
        if (t + 2 < nt) stage(t & 1, (t + 2) * 32);   // overwrite is now safe
#pragma unroll
        for (int i = 0; i < 2; ++i)
#pragma unroll
            for (int j = 0; j < 4; ++j)
                acc[i][j] = __builtin_amdgcn_mfma_f32_16x16x32_bf16(af[i], bf[j], acc[i][j], 0, 0, 0);
    }
    // epilogue: C/D layout col=lane&15, row=(lane>>4)*4+reg
    const int lr = (lane >> 4) * 4;
#pragma unroll
    for (int i = 0; i < 2; ++i) {
        int rbase = row0 + wr * 32 + i * 16 + lr;
#pragma unroll
        for (int r = 0; r < 4; ++r) {
            int row = rbase + r;
            if (MODE == 0) {
                unsigned short* cp = Cb + (size_t)row * kD;
#pragma unroll
                for (int j = 0; j < 4; ++j) {
                    int col = col0 + wc * 64 + j * 16 + l15;
                    cp[col] = f2bf(fmaxf(acc[i][j][r], 0.f));
                }
            } else if (MODE == 1) {
                float* cp = Cf + (size_t)row * kD;
#pragma unroll
                for (int j = 0; j < 4; ++j) {
                    int col = col0 + wc * 64 + j * 16 + l15;
                    cp[col] += acc[i][j][r];
                }
            } else if (MODE == 2) {
                const float* ep = Ef + (size_t)row * kD;
                float* op = Cf + edge_out_off(row);
#pragma unroll
                for (int j = 0; j < 4; ++j) {
                    int col = col0 + wc * 64 + j * 16 + l15;
                    op[col] = ep[col] + acc[i][j][r];
                }
            } else if (MODE == 3) {
                float* cp = Cf + (size_t)idxp[row] * kD;
#pragma unroll
                for (int j = 0; j < 4; ++j) {
                    int col = col0 + wc * 64 + j * 16 + l15;
                    atomicAdd(cp + col, acc[i][j][r]);
                }
            } else {
                float* cp = Cf + node_out_off(idxp[row]);
#pragma unroll
                for (int j = 0; j < 4; ++j) {
                    int col = col0 + wc * 64 + j * 16 + l15;
                    atomicAdd(cp + col, acc[i][j][r]);
                }
            }
        }
    }
}

// L0: z=0 msgb = bf16(relu(bufM @ WtM^T));  z=1 edges += bufE @ WtE^T
__global__ __launch_bounds__(256) void gemm_dual_l0(const unsigned short* __restrict__ A0,
                                                    const unsigned short* __restrict__ B0,
                                                    unsigned short* __restrict__ C0,
                                                    const unsigned short* __restrict__ A1,
                                                    const unsigned short* __restrict__ B1,
                                                    float* __restrict__ C1) {
    __shared__ char smem[24576];
    if (blockIdx.z == 0)
        gemm_body<0>(A0, B0, nullptr, C0, nullptr, nullptr, smem, blockIdx.x, blockIdx.y);
    else
        gemm_body<1>(A1, B1, C1, nullptr, nullptr, nullptr, smem, blockIdx.x, blockIdx.y);
}

// L1: z=0 msgb = bf16(relu(bufM @ WtM^T));  z=1 out_edges = edges + bufE @ WtE^T
__global__ __launch_bounds__(256) void gemm_dual_l1(const unsigned short* __restrict__ A0,
                                                    const unsigned short* __restrict__ B0,
                                                    unsigned short* __restrict__ C0,
                                                    const unsigned short* __restrict__ A1,
                                                    const unsigned short* __restrict__ B1,
                                                    float* __restrict__ outp,
                                                    const float* __restrict__ edges) {
    __shared__ char smem[24576];
    if (blockIdx.z == 0)
        gemm_body<0>(A0, B0, nullptr, C0, nullptr, nullptr, smem, blockIdx.x, blockIdx.y);
    else
        gemm_body<2>(A1, B1, outp, nullptr, edges, nullptr, smem, blockIdx.x, blockIdx.y);
}

// nodes[dst[row]] += (msgb @ WtU^T)[row]   (full K, one atomic per element)
__global__ __launch_bounds__(256) void gemm_upd_l0(const unsigned short* __restrict__ A,
                                                   const unsigned short* __restrict__ B,
                                                   float* __restrict__ C,
                                                   const int* __restrict__ dstIdx) {
    __shared__ char smem[24576];
    gemm_body<3>(A, B, C, nullptr, nullptr, dstIdx, smem, blockIdx.x, blockIdx.y);
}

// out_nodes[dst[row]] += (msgb @ WtU^T)[row]  (final layer -> d_out directly)
__global__ __launch_bounds__(256) void gemm_upd_l1(const unsigned short* __restrict__ A,
                                                   const unsigned short* __restrict__ B,
                                                   float* __restrict__ outp,
                                                   const int* __restrict__ dstIdx) {
    __shared__ char smem[24576];
    gemm_body<4>(A, B, outp, nullptr, nullptr, dstIdx, smem, blockIdx.x, blockIdx.y);
}

// ---------------------------------------------------------------------------
extern "C" void kernel_launch(void* const* d_in, const int* in_sizes, int n_in,
                              void* d_out, int out_size, void* d_ws, size_t ws_size,
                              hipStream_t stream) {
    const int*   tokens = (const int*)d_in[0];
    const int*   gids   = (const int*)d_in[1];
    const int*   eidx   = (const int*)d_in[3];
    const float* emb    = (const float*)d_in[4];
    const float* Wm     = (const float*)d_in[5];
    const float* Wu     = (const float*)d_in[6];
    const float* We     = (const float*)d_in[7];
    float* out = (float*)d_out;

    // workspace layout
    constexpr size_t szNodes = (size_t)kBNN * kD * 4;   // fp32 master
    constexpr size_t szEdges = (size_t)kBNE * kD * 4;   // fp32 master
    constexpr size_t szBufM  = (size_t)kBNE * kD * 2;   // bf16
    constexpr size_t szBufE  = (size_t)kBNE * kD * 2;   // bf16
    constexpr size_t szMsgB  = (size_t)kBNE * kD * 2;   // bf16
    char* ws = (char*)d_ws;
    float*          nodes = (float*)ws;
    float*          edges = (float*)(ws + szNodes);
    unsigned short* bufM  = (unsigned short*)(ws + szNodes + szEdges);
    unsigned short* bufE  = (unsigned short*)(ws + szNodes + szEdges + szBufM);
    unsigned short* msgb  = (unsigned short*)(ws + szNodes + szEdges + szBufM + szBufE);
    unsigned short* Wt    = (unsigned short*)(ws + szNodes + szEdges + szBufM + szBufE + szMsgB);

    const int* srcIdx = eidx;
    const int* dstIdx = eidx + kBNE;
    unsigned short* WtM = Wt;                           // [l][N][K]
    unsigned short* WtU = Wt + (size_t)2 * kD * kD;
    unsigned short* WtE = Wt + (size_t)4 * kD * kD;

    // pool (binary-search bounds) + weight transpose, one launch
    prep_kernel<<<kB * kG + 6 * 1024, 256, 0, stream>>>(
        tokens, gids, emb, nodes, edges, Wm, Wu, We, Wt);

    constexpr int mt = kBNE / 64;                // 53
    const dim3 gdual(kD / 128, mt, 2);           // 848 blocks
    const dim3 gupd(kD / 128, mt, 1);            // 424 blocks, full K

    // ---- layer 0 ----
    gather_kernel<0><<<kBNE, 256, 0, stream>>>(nodes, edges, srcIdx, dstIdx, bufM, bufE, out);
    gemm_dual_l0<<<gdual, 256, 0, stream>>>(bufM, WtM, msgb, bufE, WtE, edges);
    gemm_upd_l0<<<gupd, 256, 0, stream>>>(msgb, WtU, nodes, dstIdx);

    // ---- layer 1 (writes final values straight into d_out) ----
    gather_kernel<1><<<kBNE + kBNN, 256, 0, stream>>>(nodes, edges, srcIdx, dstIdx, bufM, bufE, out);
    gemm_dual_l1<<<gdual, 256, 0, stream>>>(bufM, WtM + (size_t)kD * kD, msgb,
                                            bufE, WtE + (size_t)kD * kD, out, edges);
    gemm_upd_l1<<<gupd, 256, 0, stream>>>(msgb, WtU + (size_t)kD * kD, out, dstIdx);
}